// Round 13
// baseline (30.588 us; speedup 1.0000x reference)
//
#include <hip/hip_runtime.h>
#include <stdint.h>

#define NB 200000
#define BB 4
#define GG 64
#define MAXPOS 128
#define BATCH 256
#define MPRE 16384                 // prefix length scanned by K1 (exactness checked in K2)
#define CHP 256                    // anchors per K1 block / per selection chunk
#define NCHP (MPRE / CHP)          // 64 chunks per image

// thresholds folded: inter - t*u >= 0  <=>  ((1+t)/t)*inter - (a1+ga) >= 0
#define CP (1.7f / 0.7f)
#define CN (1.3f / 0.3f)

// ---------------- K1: prefix-only per-anchor threshold flags + per-chunk counts ----------------
__global__ __launch_bounds__(256) void rpn_flags_kernel(
        const float* __restrict__ anchors, const float* __restrict__ gt,
        uint8_t* __restrict__ flags, uint32_t* __restrict__ chunkCnt) {
    int b = blockIdx.y;
    int tid = threadIdx.x, lane = tid & 63, wid = tid >> 6;
    __shared__ __align__(16) float4 sG[GG];
    if (tid < GG) sG[tid] = ((const float4*)gt)[b * GG + tid];
    __syncthreads();

    int i = blockIdx.x * CHP + tid;            // i < MPRE <= NB always
    float4 a = ((const float4*)anchors)[(size_t)b * NB + i];
    float na1 = -((a.z - a.x) * (a.w - a.y));
    float mp = -1.0f, mn = -1.0f;

    #pragma unroll 8
    for (int g = 0; g < GG; ++g) {
        float4 c = sG[g];                       // broadcast ds_read_b128
        float ga = (c.z - c.x) * (c.w - c.y);
        float w = fmaxf(fminf(a.z, c.z) - fmaxf(a.x, c.x), 0.0f);
        float h = fmaxf(fminf(a.w, c.w) - fmaxf(a.y, c.y), 0.0f);
        float inter = w * h;
        float s = na1 - ga;
        mp = fmaxf(mp, __builtin_fmaf(CP, inter, s));
        mn = fmaxf(mn, __builtin_fmaf(CN, inter, s));
    }

    bool p = (mp >= 0.0f);
    bool n = (mn < 0.0f);
    flags[(size_t)b * NB + i] = (uint8_t)((p ? 1 : 0) | (n ? 2 : 0));

    uint32_t pn = (p ? 1u : 0u) + (n ? 0x10000u : 0u);
    for (int off = 32; off > 0; off >>= 1) pn += __shfl_down(pn, off);
    __shared__ uint32_t wSum[4];
    if (lane == 0) wSum[wid] = pn;
    __syncthreads();
    if (tid == 0)
        chunkCnt[b * NCHP + blockIdx.x] = wSum[0] + wSum[1] + wSum[2] + wSum[3];
}

// ---------------- K2: ONE block, 4 waves/image: scan + selection + loss + finalize ----------------
// No fences, no tickets: cross-image combine is a __syncthreads().
__global__ __launch_bounds__(1024) void rpn_tail_kernel(
        const uint8_t* __restrict__ flags,
        const float* __restrict__ logits, const float* __restrict__ breg,
        const float* __restrict__ anchors, const float* __restrict__ gt,
        const uint32_t* __restrict__ chunkCnt,
        float* __restrict__ out) {
    int tid = threadIdx.x, lane = tid & 63, wid = tid >> 6;
    int b = wid & 3, wiw = wid >> 2;            // image, wave-in-image (4 waves/image)
    const uint8_t* __restrict__ F = flags + (size_t)b * NB;

    __shared__ __align__(16) float4 sG[BB * GG];        // 16 KB
    __shared__ int basP[BB][NCHP], basN[BB][NCHP];      // 2 KB
    __shared__ int sTotP[BB], sTotN[BB];
    __shared__ int sNumPos[BB], sNumNeg[BB];
    __shared__ int selPos[BB * MAXPOS];                 // 2 KB
    __shared__ int selNeg[BB * BATCH];                  // 4 KB
    __shared__ float sB[BB], sS[BB];

    if (tid < BB * GG) sG[tid] = ((const float4*)gt)[tid];
    if (tid < BB) { sB[tid] = 0.0f; sS[tid] = 0.0f; }

    // --- waves 0..3: per-image exclusive scan of 64 packed (pos, neg) chunk counts ---
    if (wid < BB) {
        int bb = wid;
        unsigned long long e = 0ULL;
        if (lane < NCHP) {
            uint32_t c = chunkCnt[bb * NCHP + lane];
            e = (unsigned long long)(c & 0xFFFFu) | ((unsigned long long)(c >> 16) << 32);
        }
        unsigned long long inc = e;
        for (int off = 1; off < 64; off <<= 1) {
            unsigned long long v = __shfl_up(inc, off);
            if (lane >= off) inc += v;
        }
        if (lane < NCHP) {
            unsigned long long ex = inc - e;
            basP[bb][lane] = (int)(ex & 0xFFFFFFFFULL);
            basN[bb][lane] = (int)(ex >> 32);
        }
        unsigned long long tot = __shfl(inc, 63);
        if (lane == 0) {
            int tp = (int)(tot & 0xFFFFFFFFULL);
            int tn = (int)(tot >> 32);
            sTotP[bb] = tp; sTotN[bb] = tn;
            int np = min(tp, MAXPOS);           // provisional; exact when fast
            sNumPos[bb] = np;
            sNumNeg[bb] = min(tn, BATCH - np);
        }
    }
    __syncthreads();

    // exactness: prefix holds >=128 pos and >=128 neg -> quotas + all selected
    // indices provably lie in the prefix (first-k-by-index semantics).
    bool fast = (sTotP[b] >= MAXPOS) && (sTotN[b] >= BATCH - MAXPOS);

    if (fast) {
        int numPos = MAXPOS, numNeg = BATCH - MAXPOS;
        for (int c = wiw; c < NCHP; c += 4) {   // 4 waves per image
            int bp = basP[b][c], bn = basN[b][c];
            if (bp >= numPos && bn >= numNeg) break;   // bases monotone, wave-uniform
            int offP = 0, offN = 0;
            #pragma unroll
            for (int s = 0; s < CHP / 64; ++s) {
                int idx = c * CHP + s * 64 + lane;     // idx < MPRE
                uint8_t f = F[idx];
                bool p = (f & 1) != 0, n = (f & 2) != 0;
                unsigned long long mpm = __ballot(p), mnm = __ballot(n);
                unsigned long long lt = (1ULL << lane) - 1ULL;
                int rp = bp + offP + __popcll(mpm & lt);
                int rn = bn + offN + __popcll(mnm & lt);
                if (p && rp < numPos) selPos[b * MAXPOS + rp] = idx;
                if (n && rn < numNeg) selNeg[b * BATCH + rn] = idx;
                offP += __popcll(mpm); offN += __popcll(mnm);
            }
        }
    } else if (wiw == 0) {
        // exact fallback (never taken for benchmark data): this image's wave0
        // scans ALL anchors, computing flags beyond the prefix on the fly.
        int totP = 0, totN = 0;
        for (int g0 = 0; g0 < NB; g0 += 64) {
            int idx = g0 + lane;
            bool p = false, n = false;
            if (idx < NB) {
                if (idx < MPRE) {
                    uint8_t f = F[idx];
                    p = (f & 1) != 0; n = (f & 2) != 0;
                } else {
                    float4 a = ((const float4*)anchors)[(size_t)b * NB + idx];
                    float na1 = -((a.z - a.x) * (a.w - a.y));
                    float mp = -1.0f, mn = -1.0f;
                    for (int g = 0; g < GG; ++g) {
                        float4 c = sG[b * GG + g];
                        float ga = (c.z - c.x) * (c.w - c.y);
                        float w = fmaxf(fminf(a.z, c.z) - fmaxf(a.x, c.x), 0.0f);
                        float h = fmaxf(fminf(a.w, c.w) - fmaxf(a.y, c.y), 0.0f);
                        float inter = w * h;
                        float s = na1 - ga;
                        mp = fmaxf(mp, __builtin_fmaf(CP, inter, s));
                        mn = fmaxf(mn, __builtin_fmaf(CN, inter, s));
                    }
                    p = (mp >= 0.0f); n = (mn < 0.0f);
                }
            }
            unsigned long long mpm = __ballot(p), mnm = __ballot(n);
            unsigned long long lt = (1ULL << lane) - 1ULL;
            int rp = totP + __popcll(mpm & lt);
            int rn = totN + __popcll(mnm & lt);
            if (p && rp < MAXPOS) selPos[b * MAXPOS + rp] = idx;
            if (n && rn < BATCH) selNeg[b * BATCH + rn] = idx;
            totP += __popcll(mpm); totN += __popcll(mnm);
            if (totP >= MAXPOS && totN >= BATCH) break;    // quotas resolvable
        }
        if (lane == 0) {
            int np = min(totP, MAXPOS);
            sNumPos[b] = np;
            sNumNeg[b] = min(totN, BATCH - np);
        }
    }
    __syncthreads();

    int numPos = sNumPos[b], numNeg = sNumNeg[b];

    // --- losses: 4 waves/image -> t = wiw*64+lane covers 0..255 ---
    float bce_acc = 0.0f, sl1_acc = 0.0f;
    int t = wiw * 64 + lane;
    if (t < numPos) {
        int i = selPos[b * MAXPOS + t];
        float x = logits[(size_t)b * NB + i];
        bce_acc += fmaxf(x, 0.0f) - x + log1pf(expf(-fabsf(x)));
        float4 a = ((const float4*)anchors)[(size_t)b * NB + i];
        float a1 = (a.z - a.x) * (a.w - a.y);
        float ib = -1.0f, ub = 1.0f;
        int bi = 0;
        #pragma unroll 8
        for (int g = 0; g < GG; ++g) {
            float4 c = sG[b * GG + g];
            float ga = (c.z - c.x) * (c.w - c.y);
            float w = fmaxf(fminf(a.z, c.z) - fmaxf(a.x, c.x), 0.0f);
            float h = fmaxf(fminf(a.w, c.w) - fmaxf(a.y, c.y), 0.0f);
            float inter = w * h;
            float u = (a1 + ga) - inter;
            bool better = inter * ub > ib * u;   // first-max argmax, cross-mult
            ib = better ? inter : ib;
            ub = better ? u : ub;
            bi = better ? g : bi;
        }
        float4 t4 = sG[b * GG + bi];
        float acx = (a.x + a.z) / 2.0f, acy = (a.y + a.w) / 2.0f;
        float aw = a.z - a.x, ah = a.w - a.y;
        float tcx = (t4.x + t4.z) / 2.0f, tcy = (t4.y + t4.w) / 2.0f;
        float tw = t4.z - t4.x, th = t4.w - t4.y;
        float d0 = (tcx - acx) / aw;
        float d1 = (tcy - acy) / ah;
        float d2 = logf(tw / aw);
        float d3 = logf(th / ah);
        float4 r = ((const float4*)breg)[(size_t)b * NB + i];
        float df;
        df = fabsf(r.x - d0); sl1_acc += (df < 1.0f) ? 0.5f * df * df : df - 0.5f;
        df = fabsf(r.y - d1); sl1_acc += (df < 1.0f) ? 0.5f * df * df : df - 0.5f;
        df = fabsf(r.z - d2); sl1_acc += (df < 1.0f) ? 0.5f * df * df : df - 0.5f;
        df = fabsf(r.w - d3); sl1_acc += (df < 1.0f) ? 0.5f * df * df : df - 0.5f;
    }
    if (t < numNeg) {
        int i = selNeg[b * BATCH + t];
        float x = logits[(size_t)b * NB + i];
        bce_acc += fmaxf(x, 0.0f) + log1pf(expf(-fabsf(x)));
    }
    for (int off = 32; off > 0; off >>= 1) {
        bce_acc += __shfl_down(bce_acc, off);
        sl1_acc += __shfl_down(sl1_acc, off);
    }
    if (lane == 0) {
        atomicAdd(&sB[b], bce_acc);
        atomicAdd(&sS[b], sl1_acc);
    }
    __syncthreads();

    if (tid == 0) {
        float bce = 0.0f, val = 0.0f, sl1 = 0.0f, np = 0.0f;
        #pragma unroll
        for (int w = 0; w < BB; ++w) {
            bce += sB[w]; sl1 += sS[w];
            val += (float)(sNumPos[w] + sNumNeg[w]);
            np  += (float)sNumPos[w];
        }
        out[0] = bce / fmaxf(val, 1.0f);
        out[1] = sl1 / fmaxf(np * 4.0f, 1.0f);
    }
}

extern "C" void kernel_launch(void* const* d_in, const int* in_sizes, int n_in,
                              void* d_out, int out_size, void* d_ws, size_t ws_size,
                              hipStream_t stream) {
    const float* cls  = (const float*)d_in[0];  // [B,N,1]
    const float* breg = (const float*)d_in[1];  // [B,N,4]
    const float* anch = (const float*)d_in[2];  // [B,N,4]
    const float* gt   = (const float*)d_in[3];  // [B,G,4]
    float* out = (float*)d_out;

    uint8_t*  flags    = (uint8_t*)d_ws;                            // B*N (prefix used)
    uint32_t* chunkCnt = (uint32_t*)((uint8_t*)d_ws + 800000);      // B*NCHP

    dim3 g1(NCHP, BB);
    rpn_flags_kernel<<<g1, 256, 0, stream>>>(anch, gt, flags, chunkCnt);
    rpn_tail_kernel<<<1, 1024, 0, stream>>>(flags, cls, breg, anch, gt,
                                            chunkCnt, out);
}